// Round 1
// baseline (3820.882 us; speedup 1.0000x reference)
//
#include <hip/hip_runtime.h>
#include <hip/hip_bf16.h>
#include <math.h>

// Problem constants
#define LAYERS 4
#define DMODEL 512
#define NH 8
#define DH 64
#define DFF 2048
#define NB 4
#define S_LEN 2048
#define MROWS (NB * S_LEN)      // 8192
#define CHUNK 128
#define NCHUNK (S_LEN / CHUNK)  // 16
#define ATT_EPS 1e-6f
#define LN_EPS 1e-5f

// ---------------------------------------------------------------------------
// GEMM: C[M,N] = act(A[M,K] @ W[K,N] + bias[N] (+ C if ACCUM))
// ACT: 0=none, 1=elu+1, 2=exact gelu
// 64x64 tile, BK=16, 256 threads, 4x4 microtile.
// ---------------------------------------------------------------------------
template <int ACT, bool ACCUM>
__global__ __launch_bounds__(256) void gemm_kernel(
    const float* __restrict__ A, const float* __restrict__ W,
    const float* __restrict__ bias, float* __restrict__ C,
    int M, int N, int K)
{
    __shared__ float As[16][68];  // k-major, transposed A tile (pad 68)
    __shared__ float Bs[16][68];

    const int t  = threadIdx.x;
    const int m0 = blockIdx.x * 64;
    const int n0 = blockIdx.y * 64;
    const int tx = t & 15, ty = t >> 4;

    const int arow = t >> 2;          // 0..63
    const int akc  = (t & 3) << 2;    // 0,4,8,12
    const int bk   = t >> 4;          // 0..15
    const int bn   = (t & 15) << 2;   // 0..60

    float acc[4][4];
#pragma unroll
    for (int i = 0; i < 4; ++i)
#pragma unroll
        for (int j = 0; j < 4; ++j) acc[i][j] = 0.f;

    for (int kk = 0; kk < K; kk += 16) {
        float4 av = *(const float4*)&A[(long)(m0 + arow) * K + kk + akc];
        float4 bv = *(const float4*)&W[(long)(kk + bk) * N + n0 + bn];
        As[akc + 0][arow] = av.x;
        As[akc + 1][arow] = av.y;
        As[akc + 2][arow] = av.z;
        As[akc + 3][arow] = av.w;
        *(float4*)&Bs[bk][bn] = bv;
        __syncthreads();
#pragma unroll
        for (int k = 0; k < 16; ++k) {
            float4 af = *(const float4*)&As[k][ty << 2];
            float4 bf = *(const float4*)&Bs[k][tx << 2];
            const float ar[4] = {af.x, af.y, af.z, af.w};
            const float br[4] = {bf.x, bf.y, bf.z, bf.w};
#pragma unroll
            for (int i = 0; i < 4; ++i)
#pragma unroll
                for (int j = 0; j < 4; ++j) acc[i][j] += ar[i] * br[j];
        }
        __syncthreads();
    }

#pragma unroll
    for (int i = 0; i < 4; ++i) {
        const int row = m0 + (ty << 2) + i;
#pragma unroll
        for (int j = 0; j < 4; ++j) {
            const int col = n0 + (tx << 2) + j;
            float v = acc[i][j] + bias[col];
            if (ACCUM) v += C[(long)row * N + col];
            if (ACT == 1) v = (v > 0.f) ? (v + 1.f) : expf(v);
            else if (ACT == 2) v = 0.5f * v * (1.f + erff(v * 0.70710678118654752f));
            C[(long)row * N + col] = v;
        }
    }
}

// ---------------------------------------------------------------------------
// Attention stage 1: per (b,h,chunk) partial states KV = K^T V (64x64), z = sum K
// ---------------------------------------------------------------------------
__global__ __launch_bounds__(256) void attn_stage1(
    const float* __restrict__ Kf, const float* __restrict__ Vf,
    float* __restrict__ KVp, float* __restrict__ zp)
{
    const int c = blockIdx.x, hh = blockIdx.y, bb = blockIdx.z;
    const int t = threadIdx.x;
    __shared__ float Ks[CHUNK][DH];
    __shared__ float Vs[CHUNK][DH];

    const long rowbase = (long)(bb * S_LEN + c * CHUNK);
    const int colbase = hh * DH;

    const int lc = (t & 15) << 2;
    for (int r = 0; r < CHUNK; r += 16) {
        const int row = r + (t >> 4);
        *(float4*)&Ks[row][lc] = *(const float4*)(Kf + (rowbase + row) * DMODEL + colbase + lc);
        *(float4*)&Vs[row][lc] = *(const float4*)(Vf + (rowbase + row) * DMODEL + colbase + lc);
    }
    __syncthreads();

    const int d  = t >> 2;
    const int e0 = (t & 3) << 4;  // 16 e-values
    float acc[16];
#pragma unroll
    for (int i = 0; i < 16; ++i) acc[i] = 0.f;

    for (int j = 0; j < CHUNK; ++j) {
        const float kd = Ks[j][d];
#pragma unroll
        for (int i = 0; i < 16; i += 4) {
            float4 vv = *(const float4*)&Vs[j][e0 + i];
            acc[i + 0] += kd * vv.x;
            acc[i + 1] += kd * vv.y;
            acc[i + 2] += kd * vv.z;
            acc[i + 3] += kd * vv.w;
        }
    }
    float* dst = KVp + (((long)(bb * NH + hh) * NCHUNK + c) * DH * DH) + d * DH + e0;
#pragma unroll
    for (int i = 0; i < 16; ++i) dst[i] = acc[i];

    if (t < DH) {
        float s = 0.f;
        for (int j = 0; j < CHUNK; ++j) s += Ks[j][t];
        zp[((long)(bb * NH + hh) * NCHUNK + c) * DH + t] = s;
    }
}

// ---------------------------------------------------------------------------
// Attention stage 2: per (b,h) exclusive prefix over the 16 chunk states
// ---------------------------------------------------------------------------
__global__ __launch_bounds__(256) void attn_stage2(float* __restrict__ KVp,
                                                   float* __restrict__ zp)
{
    const int bh = blockIdx.x;  // 0..31
    const int t = threadIdx.x;
    for (int e = t; e < DH * DH; e += 256) {
        float run = 0.f;
        const long base = (long)bh * NCHUNK * DH * DH + e;
#pragma unroll
        for (int c = 0; c < NCHUNK; ++c) {
            const float tmp = KVp[base + c * DH * DH];
            KVp[base + c * DH * DH] = run;
            run += tmp;
        }
    }
    if (t < DH) {
        float run = 0.f;
        const long base = (long)bh * NCHUNK * DH + t;
#pragma unroll
        for (int c = 0; c < NCHUNK; ++c) {
            const float tmp = zp[base + c * DH];
            zp[base + c * DH] = run;
            run += tmp;
        }
    }
}

// ---------------------------------------------------------------------------
// Attention stage 3: per (b,h,chunk): out_i = (q_i@KV_pre + sum_{j<=i} s_ij v_j)
//                                   / (q_i@z_pre + sum_{j<=i} s_ij + eps)
// 128 threads, one per row of the chunk.
// ---------------------------------------------------------------------------
__global__ __launch_bounds__(128) void attn_stage3(
    const float* __restrict__ Qf, const float* __restrict__ Kf,
    const float* __restrict__ Vf, const float* __restrict__ KVp,
    const float* __restrict__ zp, float* __restrict__ Af)
{
    const int c = blockIdx.x, hh = blockIdx.y, bb = blockIdx.z;
    const int t = threadIdx.x;  // 0..127
    __shared__ float Ks[CHUNK][DH];
    __shared__ float Vs[CHUNK][DH];
    __shared__ float KVs[DH][DH];
    __shared__ float zs[DH];

    const long rowbase = (long)(bb * S_LEN + c * CHUNK);
    const int colbase = hh * DH;
    const int lc = (t & 15) << 2;

    // Phase A: stage Q through Ks (coalesced), pull own row into registers
    for (int r = 0; r < CHUNK; r += 8) {
        const int row = r + (t >> 4);
        *(float4*)&Ks[row][lc] = *(const float4*)(Qf + (rowbase + row) * DMODEL + colbase + lc);
    }
    __syncthreads();
    float q[DH];
#pragma unroll
    for (int d = 0; d < DH; d += 4) {
        float4 v = *(const float4*)&Ks[t][d];
        q[d] = v.x; q[d + 1] = v.y; q[d + 2] = v.z; q[d + 3] = v.w;
    }
    __syncthreads();

    // Phase B: load K, V, KV_pre, z_pre
    for (int r = 0; r < CHUNK; r += 8) {
        const int row = r + (t >> 4);
        *(float4*)&Ks[row][lc] = *(const float4*)(Kf + (rowbase + row) * DMODEL + colbase + lc);
        *(float4*)&Vs[row][lc] = *(const float4*)(Vf + (rowbase + row) * DMODEL + colbase + lc);
    }
    {
        float* kvflat = &KVs[0][0];
        const float* kvsrc = KVp + ((long)(bb * NH + hh) * NCHUNK + c) * DH * DH;
        for (int e = t * 4; e < DH * DH; e += 128 * 4)
            *(float4*)&kvflat[e] = *(const float4*)&kvsrc[e];
        if (t < DH) zs[t] = zp[((long)(bb * NH + hh) * NCHUNK + c) * DH + t];
    }
    __syncthreads();

    // Phase C: compute
    float o[DH];
#pragma unroll
    for (int e = 0; e < DH; ++e) o[e] = 0.f;

    // o += q @ KV_pre
#pragma unroll
    for (int d = 0; d < DH; ++d) {
        const float qd = q[d];
#pragma unroll
        for (int e = 0; e < DH; e += 4) {
            float4 kv = *(const float4*)&KVs[d][e];
            o[e + 0] += qd * kv.x;
            o[e + 1] += qd * kv.y;
            o[e + 2] += qd * kv.z;
            o[e + 3] += qd * kv.w;
        }
    }
    float den = 0.f;
#pragma unroll
    for (int d = 0; d < DH; ++d) den += q[d] * zs[d];

    for (int j = 0; j < CHUNK; ++j) {
        float s = 0.f;
#pragma unroll
        for (int d = 0; d < DH; d += 4) {
            float4 kv = *(const float4*)&Ks[j][d];
            s += q[d] * kv.x + q[d + 1] * kv.y + q[d + 2] * kv.z + q[d + 3] * kv.w;
        }
        if (j <= t) {
            den += s;
#pragma unroll
            for (int e = 0; e < DH; e += 4) {
                float4 vv = *(const float4*)&Vs[j][e];
                o[e + 0] += s * vv.x;
                o[e + 1] += s * vv.y;
                o[e + 2] += s * vv.z;
                o[e + 3] += s * vv.w;
            }
        }
    }

    const float inv = 1.f / (den + ATT_EPS);
    float* dst = Af + (rowbase + t) * DMODEL + colbase;
#pragma unroll
    for (int e = 0; e < DH; e += 4) {
        float4 vv;
        vv.x = o[e + 0] * inv;
        vv.y = o[e + 1] * inv;
        vv.z = o[e + 2] * inv;
        vv.w = o[e + 3] * inv;
        *(float4*)&dst[e] = vv;
    }
}

// ---------------------------------------------------------------------------
// LayerNorm over last dim (512), one wave per row, in-place.
// ---------------------------------------------------------------------------
__global__ __launch_bounds__(64) void ln_kernel(float* __restrict__ X,
                                                const float* __restrict__ g,
                                                const float* __restrict__ b)
{
    const long row = blockIdx.x;
    const int t = threadIdx.x;
    float* xr = X + row * DMODEL;
    float4 x0 = *(const float4*)&xr[t * 4];
    float4 x1 = *(const float4*)&xr[256 + t * 4];

    float s  = x0.x + x0.y + x0.z + x0.w + x1.x + x1.y + x1.z + x1.w;
    float sq = x0.x * x0.x + x0.y * x0.y + x0.z * x0.z + x0.w * x0.w +
               x1.x * x1.x + x1.y * x1.y + x1.z * x1.z + x1.w * x1.w;
#pragma unroll
    for (int m = 1; m < 64; m <<= 1) {
        s  += __shfl_xor(s, m);
        sq += __shfl_xor(sq, m);
    }
    const float mu  = s * (1.f / DMODEL);
    const float var = sq * (1.f / DMODEL) - mu * mu;
    const float r   = rsqrtf(var + LN_EPS);

    const int c0 = t * 4, c1 = 256 + t * 4;
    float4 g0 = *(const float4*)&g[c0], g1v = *(const float4*)&g[c1];
    float4 b0 = *(const float4*)&b[c0], b1v = *(const float4*)&b[c1];
    float4 y0, y1;
    y0.x = (x0.x - mu) * r * g0.x + b0.x;
    y0.y = (x0.y - mu) * r * g0.y + b0.y;
    y0.z = (x0.z - mu) * r * g0.z + b0.z;
    y0.w = (x0.w - mu) * r * g0.w + b0.w;
    y1.x = (x1.x - mu) * r * g1v.x + b1v.x;
    y1.y = (x1.y - mu) * r * g1v.y + b1v.y;
    y1.z = (x1.z - mu) * r * g1v.z + b1v.z;
    y1.w = (x1.w - mu) * r * g1v.w + b1v.w;
    *(float4*)&xr[c0] = y0;
    *(float4*)&xr[c1] = y1;
}

// ---------------------------------------------------------------------------
extern "C" void kernel_launch(void* const* d_in, const int* in_sizes, int n_in,
                              void* d_out, int out_size, void* d_ws, size_t ws_size,
                              hipStream_t stream)
{
    const float* h   = (const float*)d_in[0];
    const float* Wq  = (const float*)d_in[1];
    const float* bq  = (const float*)d_in[2];
    const float* Wk  = (const float*)d_in[3];
    const float* bk  = (const float*)d_in[4];
    const float* Wv  = (const float*)d_in[5];
    const float* bv  = (const float*)d_in[6];
    const float* Wo  = (const float*)d_in[7];
    const float* bo  = (const float*)d_in[8];
    const float* W1  = (const float*)d_in[9];
    const float* b1  = (const float*)d_in[10];
    const float* W2  = (const float*)d_in[11];
    const float* b2  = (const float*)d_in[12];
    const float* g1  = (const float*)d_in[13];
    const float* be1 = (const float*)d_in[14];
    const float* g2  = (const float*)d_in[15];
    const float* be2 = (const float*)d_in[16];
    const float* gf  = (const float*)d_in[17];
    const float* bef = (const float*)d_in[18];

    float* x   = (float*)d_out;              // running activation [8192,512]
    float* buf = (float*)d_ws;               // 16,777,216 floats (64 MB)
    float* qb  = buf;                        // [8192,512] slices during attention
    float* kb  = buf + 1 * 4194304;
    float* vb  = buf + 2 * 4194304;
    float* ab  = buf + 3 * 4194304;
    float* KVp = buf + 4 * 4194304;          // [B,H,NC,64,64] = 2,097,152 floats
    float* zpb = KVp + 2097152;              // [B,H,NC,64]    = 32,768 floats

    const int M = MROWS, D = DMODEL, DF = DFF;

    hipMemcpyAsync(x, h, (size_t)M * D * sizeof(float),
                   hipMemcpyDeviceToDevice, stream);

    for (int l = 0; l < LAYERS; ++l) {
        const float* Wq_l = Wq + (size_t)l * D * D;
        const float* Wk_l = Wk + (size_t)l * D * D;
        const float* Wv_l = Wv + (size_t)l * D * D;
        const float* Wo_l = Wo + (size_t)l * D * D;
        const float* W1_l = W1 + (size_t)l * D * DF;
        const float* W2_l = W2 + (size_t)l * DF * D;

        // q/k/v projections (+ feature map phi = elu+1 on q,k)
        gemm_kernel<1, false><<<dim3(M / 64, D / 64), 256, 0, stream>>>(x, Wq_l, bq + l * D, qb, M, D, D);
        gemm_kernel<1, false><<<dim3(M / 64, D / 64), 256, 0, stream>>>(x, Wk_l, bk + l * D, kb, M, D, D);
        gemm_kernel<0, false><<<dim3(M / 64, D / 64), 256, 0, stream>>>(x, Wv_l, bv + l * D, vb, M, D, D);

        // chunked causal linear attention
        attn_stage1<<<dim3(NCHUNK, NH, NB), 256, 0, stream>>>(kb, vb, KVp, zpb);
        attn_stage2<<<dim3(NB * NH), 256, 0, stream>>>(KVp, zpb);
        attn_stage3<<<dim3(NCHUNK, NH, NB), 128, 0, stream>>>(qb, kb, vb, KVp, zpb, ab);

        // out projection + residual, then LN1
        gemm_kernel<0, true><<<dim3(M / 64, D / 64), 256, 0, stream>>>(ab, Wo_l, bo + l * D, x, M, D, D);
        ln_kernel<<<dim3(M), 64, 0, stream>>>(x, g1 + l * D, be1 + l * D);

        // FFN: hidden = gelu(x@W1+b1); x += hidden@W2+b2; LN2
        gemm_kernel<2, false><<<dim3(M / 64, DF / 64), 256, 0, stream>>>(x, W1_l, b1 + l * DF, buf, M, DF, D);
        gemm_kernel<0, true><<<dim3(M / 64, D / 64), 256, 0, stream>>>(buf, W2_l, b2 + l * D, x, M, D, DF);
        ln_kernel<<<dim3(M), 64, 0, stream>>>(x, g2 + l * D, be2 + l * D);
    }

    ln_kernel<<<dim3(M), 64, 0, stream>>>(x, gf, bef);
}

// Round 2
// 1319.734 us; speedup vs baseline: 2.8952x; 2.8952x over previous
//
#include <hip/hip_runtime.h>
#include <hip/hip_bf16.h>
#include <math.h>

#define LAYERS 4
#define DMODEL 512
#define NH 8
#define DH 64
#define DFF 2048
#define NB 4
#define S_LEN 2048
#define MROWS 8192
#define CHUNK 64
#define NCHUNK 32            // S_LEN / CHUNK
#define ATT_EPS 1e-6f
#define LN_EPS 1e-5f
#define SEGSTRIDE (MROWS * DMODEL)   // 4194304 elems per q/k/v segment

typedef __attribute__((ext_vector_type(8))) short short8v;   // 8 bf16
typedef __attribute__((ext_vector_type(4))) float f32x4;

__device__ __forceinline__ float b2f(unsigned short u) {
    union { float f; unsigned u; } c; c.u = ((unsigned)u) << 16; return c.f;
}
__device__ __forceinline__ unsigned short f2b(float f) {
    union { float f; unsigned u; } c; c.f = f;
    unsigned r = c.u + 0x7FFFu + ((c.u >> 16) & 1u);
    return (unsigned short)(r >> 16);
}
__device__ __forceinline__ void gload16(const void* g, void* l) {
    __builtin_amdgcn_global_load_lds(
        (const __attribute__((address_space(1))) void*)g,
        (__attribute__((address_space(3))) void*)l, 16, 0, 0);
}
__device__ __forceinline__ float elu1f(float v) {
    return (v > 0.f) ? (v + 1.f) : expf(v);
}
__device__ __forceinline__ float geluf(float v) {
    return 0.5f * v * (1.f + erff(v * 0.70710678118654752f));
}

// ---------------------------------------------------------------------------
// bf16 MFMA GEMM: C[M,N] = act(A[M,K] @ W[K,N] + bias) (+C32 if ACCUM)
// A: bf16 row-major [M][K]. WT: bf16 [N][K] (W transposed).
// ACT: 0=none, 1=elu+1, 2=gelu, 3=qkv-fused (col segs of 512: seg<2 elu+1)
// 128x128 tile, BK=32, 256 threads (4 waves, 2x2), 16x16x32 MFMA.
// ---------------------------------------------------------------------------
template <int ACT, bool ACCUM, bool WF32, bool WBF16>
__global__ __launch_bounds__(256) void gemm_bf16(
    const unsigned short* __restrict__ A,
    const unsigned short* __restrict__ WT,
    const float* __restrict__ b0, const float* __restrict__ b1,
    const float* __restrict__ b2,
    float* __restrict__ C32, unsigned short* __restrict__ Cbf,
    int M, int N, int K)
{
    __shared__ short As[128 * 32];
    __shared__ short Bs[128 * 32];

    const int t = threadIdx.x;
    const int m0 = blockIdx.x * 128, n0 = blockIdx.y * 128;
    const int lane = t & 63, wid = t >> 6;
    const int wm = (wid >> 1) * 64, wn = (wid & 1) * 64;
    const int fr = lane & 15, kg = lane >> 4;

    // staging coords: elem = issue*2048 + t*8 ; row = elem>>5, k = elem&31
    const int srow = t >> 2;
    const int sk = (t & 3) * 8;

    f32x4 acc[4][4];
#pragma unroll
    for (int m = 0; m < 4; ++m)
#pragma unroll
        for (int n = 0; n < 4; ++n) acc[m][n] = (f32x4){0.f, 0.f, 0.f, 0.f};

    const unsigned short* Ar0 = A + (size_t)(m0 + srow) * K + sk;
    const unsigned short* Ar1 = A + (size_t)(m0 + srow + 64) * K + sk;
    const unsigned short* Br0 = WT + (size_t)(n0 + srow) * K + sk;
    const unsigned short* Br1 = WT + (size_t)(n0 + srow + 64) * K + sk;

    for (int kk = 0; kk < K; kk += 32) {
        gload16(Ar0 + kk, As + t * 8);
        gload16(Ar1 + kk, As + t * 8 + 2048);
        gload16(Br0 + kk, Bs + t * 8);
        gload16(Br1 + kk, Bs + t * 8 + 2048);
        __syncthreads();

        short8v a[4], b[4];
#pragma unroll
        for (int m = 0; m < 4; ++m)
            a[m] = *(const short8v*)(As + (wm + m * 16 + fr) * 32 + kg * 8);
#pragma unroll
        for (int n = 0; n < 4; ++n)
            b[n] = *(const short8v*)(Bs + (wn + n * 16 + fr) * 32 + kg * 8);
#pragma unroll
        for (int m = 0; m < 4; ++m)
#pragma unroll
            for (int n = 0; n < 4; ++n)
                acc[m][n] = __builtin_amdgcn_mfma_f32_16x16x32_bf16(
                    a[m], b[n], acc[m][n], 0, 0, 0);
        __syncthreads();
    }

    // epilogue
    const int seg = n0 >> 9;  // which 512-col segment (ACT==3)
    const float* bias = (ACT == 3) ? (seg == 0 ? b0 : (seg == 1 ? b1 : b2)) : b0;

#pragma unroll
    for (int m = 0; m < 4; ++m)
#pragma unroll
        for (int n = 0; n < 4; ++n)
#pragma unroll
            for (int j = 0; j < 4; ++j) {
                const int row = m0 + wm + m * 16 + (lane >> 4) * 4 + j;
                const int col = n0 + wn + n * 16 + fr;
                const int colin = col - seg * 512;
                float v = acc[m][n][j] + ((ACT == 3) ? bias[colin] : bias[col]);
                if (ACCUM) v += C32[(size_t)row * N + col];
                if (ACT == 1) v = elu1f(v);
                else if (ACT == 2) v = geluf(v);
                else if (ACT == 3) { if (seg < 2) v = elu1f(v); }
                if (WF32) C32[(size_t)row * N + col] = v;
                if (WBF16) {
                    if (ACT == 3)
                        Cbf[(size_t)seg * SEGSTRIDE + (size_t)row * 512 + colin] = f2b(v);
                    else
                        Cbf[(size_t)row * N + col] = f2b(v);
                }
            }
}

// ---------------------------------------------------------------------------
// Weight transpose + bf16: W [K][N] f32 -> WT [N][K] bf16
// ---------------------------------------------------------------------------
__global__ __launch_bounds__(256) void transpose_to_bf16(
    const float* __restrict__ W, unsigned short* __restrict__ WT, int K, int N)
{
    __shared__ float tile[32][33];
    const int k0 = blockIdx.x * 32, n0 = blockIdx.y * 32;
    const int tx = threadIdx.x & 31, ty = threadIdx.x >> 5;
#pragma unroll
    for (int i = ty; i < 32; i += 8)
        tile[i][tx] = W[(size_t)(k0 + i) * N + n0 + tx];
    __syncthreads();
#pragma unroll
    for (int i = ty; i < 32; i += 8)
        WT[(size_t)(n0 + i) * K + k0 + tx] = f2b(tile[tx][i]);
}

// ---------------------------------------------------------------------------
// input convert: h f32 -> x f32 copy + xb bf16
// ---------------------------------------------------------------------------
__global__ __launch_bounds__(256) void cvt_in(
    const float* __restrict__ h, float* __restrict__ x,
    unsigned short* __restrict__ xb, int n)
{
    const int i = (blockIdx.x * 256 + threadIdx.x) * 8;
    if (i >= n) return;
    f32x4 a = *(const f32x4*)(h + i);
    f32x4 b = *(const f32x4*)(h + i + 4);
    *(f32x4*)(x + i) = a;
    *(f32x4*)(x + i + 4) = b;
    short8v p;
    p[0] = f2b(a[0]); p[1] = f2b(a[1]); p[2] = f2b(a[2]); p[3] = f2b(a[3]);
    p[4] = f2b(b[0]); p[5] = f2b(b[1]); p[6] = f2b(b[2]); p[7] = f2b(b[3]);
    *(short8v*)(xb + i) = p;
}

// ---------------------------------------------------------------------------
// Attention stage 1: per (b,h,chunk of 64) states KV = K^T V, z = colsum K
// ---------------------------------------------------------------------------
__global__ __launch_bounds__(256) void attn_stage1(
    const unsigned short* __restrict__ Kf, const unsigned short* __restrict__ Vf,
    float* __restrict__ KVp, float* __restrict__ zp)
{
    const int c = blockIdx.x, hh = blockIdx.y, bb = blockIdx.z;
    const int t = threadIdx.x;
    __shared__ float Ks[CHUNK][68];
    __shared__ float Vs[CHUNK][68];

    const size_t rowbase = (size_t)(bb * S_LEN + c * CHUNK);
    const int colbase = hh * DH;
    const int r = t >> 2, cs = (t & 3) * 16;
    {
        const unsigned short* kp = Kf + (rowbase + r) * DMODEL + colbase + cs;
        const unsigned short* vp = Vf + (rowbase + r) * DMODEL + colbase + cs;
        short8v k0 = *(const short8v*)kp, k1 = *(const short8v*)(kp + 8);
        short8v v0 = *(const short8v*)vp, v1 = *(const short8v*)(vp + 8);
#pragma unroll
        for (int i = 0; i < 8; ++i) {
            Ks[r][cs + i] = b2f((unsigned short)k0[i]);
            Ks[r][cs + 8 + i] = b2f((unsigned short)k1[i]);
            Vs[r][cs + i] = b2f((unsigned short)v0[i]);
            Vs[r][cs + 8 + i] = b2f((unsigned short)v1[i]);
        }
    }
    __syncthreads();

    const int d = t >> 2, e0 = (t & 3) * 16;
    float acc[16];
#pragma unroll
    for (int i = 0; i < 16; ++i) acc[i] = 0.f;
    for (int j = 0; j < CHUNK; ++j) {
        const float kd = Ks[j][d];
#pragma unroll
        for (int i = 0; i < 16; ++i) acc[i] += kd * Vs[j][e0 + i];
    }
    float* dst = KVp + ((size_t)((bb * NH + hh) * NCHUNK + c)) * (DH * DH) + d * DH + e0;
#pragma unroll
    for (int i = 0; i < 16; i += 4)
        *(f32x4*)(dst + i) = (f32x4){acc[i], acc[i + 1], acc[i + 2], acc[i + 3]};

    if (t < DH) {
        float s = 0.f;
        for (int j = 0; j < CHUNK; ++j) s += Ks[j][t];
        zp[((size_t)(bb * NH + hh) * NCHUNK + c) * DH + t] = s;
    }
}

// ---------------------------------------------------------------------------
// Attention stage 2: exclusive prefix over 32 chunk states per (b,h)
// ---------------------------------------------------------------------------
__global__ __launch_bounds__(256) void attn_stage2(float* __restrict__ KVp,
                                                   float* __restrict__ zp)
{
    const int bh = blockIdx.x;
    const int t = threadIdx.x;
    for (int e = t; e < DH * DH; e += 256) {
        float run = 0.f;
        const size_t base = (size_t)bh * NCHUNK * DH * DH + e;
#pragma unroll 4
        for (int c = 0; c < NCHUNK; ++c) {
            const float tmp = KVp[base + (size_t)c * DH * DH];
            KVp[base + (size_t)c * DH * DH] = run;
            run += tmp;
        }
    }
    if (t < DH) {
        float run = 0.f;
        const size_t base = (size_t)bh * NCHUNK * DH + t;
#pragma unroll 4
        for (int c = 0; c < NCHUNK; ++c) {
            const float tmp = zp[base + c * DH];
            zp[base + c * DH] = run;
            run += tmp;
        }
    }
}

// ---------------------------------------------------------------------------
// Attention stage 3: 256 threads = 64 rows x 4 e-slices of 16.
// out_i = (q_i@KV_pre + sum_{j<=i} s_ij v_j) / (q_i@z_pre + sum_{j<=i} s_ij + eps)
// ---------------------------------------------------------------------------
__global__ __launch_bounds__(256) void attn_stage3(
    const unsigned short* __restrict__ Qf, const unsigned short* __restrict__ Kf,
    const unsigned short* __restrict__ Vf, const float* __restrict__ KVp,
    const float* __restrict__ zp, unsigned short* __restrict__ Af)
{
    const int c = blockIdx.x, hh = blockIdx.y, bb = blockIdx.z;
    const int t = threadIdx.x;
    const int r = t >> 2, eg = t & 3, e0 = eg * 16, wid = t >> 6;

    __shared__ float Ksf[CHUNK][68];
    __shared__ float Vsf[CHUNK][68];
    __shared__ float KVs[DH * DH];
    __shared__ float zsh[DH];

    const size_t rowbase = (size_t)(bb * S_LEN + c * CHUNK);
    const int colbase = hh * DH;

    {   // K, V chunk -> LDS (f32)
        const int cs = (t & 3) * 16;
        const unsigned short* kp = Kf + (rowbase + r) * DMODEL + colbase + cs;
        const unsigned short* vp = Vf + (rowbase + r) * DMODEL + colbase + cs;
        short8v k0 = *(const short8v*)kp, k1 = *(const short8v*)(kp + 8);
        short8v v0 = *(const short8v*)vp, v1 = *(const short8v*)(vp + 8);
#pragma unroll
        for (int i = 0; i < 8; ++i) {
            Ksf[r][cs + i] = b2f((unsigned short)k0[i]);
            Ksf[r][cs + 8 + i] = b2f((unsigned short)k1[i]);
            Vsf[r][cs + i] = b2f((unsigned short)v0[i]);
            Vsf[r][cs + 8 + i] = b2f((unsigned short)v1[i]);
        }
    }
    {   // KV_pre, z_pre -> LDS
        const float* kvsrc = KVp + ((size_t)((bb * NH + hh) * NCHUNK + c)) * (DH * DH);
#pragma unroll
        for (int e = t * 4; e < DH * DH; e += 1024)
            *(f32x4*)&KVs[e] = *(const f32x4*)&kvsrc[e];
        if (t < DH)
            zsh[t] = zp[((size_t)(bb * NH + hh) * NCHUNK + c) * DH + t];
    }
    // q row -> registers
    float q[DH];
    {
        const unsigned short* qp = Qf + (rowbase + r) * DMODEL + colbase;
#pragma unroll
        for (int d = 0; d < DH; d += 8) {
            short8v qv = *(const short8v*)(qp + d);
#pragma unroll
            for (int i = 0; i < 8; ++i) q[d + i] = b2f((unsigned short)qv[i]);
        }
    }
    __syncthreads();

    float o[16];
#pragma unroll
    for (int i = 0; i < 16; ++i) o[i] = 0.f;
    float den = 0.f;

    // o += q @ KV_pre (own e-slice); den += q . z_pre
#pragma unroll
    for (int d = 0; d < DH; ++d) {
        const float qd = q[d];
        const float* kvr = &KVs[d * DH + e0];
#pragma unroll
        for (int i = 0; i < 16; i += 4) {
            f32x4 kv = *(const f32x4*)(kvr + i);
            o[i + 0] += qd * kv[0];
            o[i + 1] += qd * kv[1];
            o[i + 2] += qd * kv[2];
            o[i + 3] += qd * kv[3];
        }
        den += qd * zsh[d];
    }

    // intra-chunk causal part; wave-uniform early exit at jmax
    const int jmax = wid * 16 + 15;
    for (int j = 0; j <= jmax; ++j) {
        float s = 0.f;
#pragma unroll
        for (int d = 0; d < DH; d += 4) {
            f32x4 kk = *(const f32x4*)&Ksf[j][d];
            s += q[d] * kk[0] + q[d + 1] * kk[1] + q[d + 2] * kk[2] + q[d + 3] * kk[3];
        }
        if (j <= r) {
            den += s;
            const float* vr = &Vsf[j][e0];
#pragma unroll
            for (int i = 0; i < 16; ++i) o[i] += s * vr[i];
        }
    }

    const float inv = 1.f / (den + ATT_EPS);
    unsigned short* dst = Af + (rowbase + r) * DMODEL + colbase + e0;
    short8v p0, p1;
#pragma unroll
    for (int i = 0; i < 8; ++i) {
        p0[i] = f2b(o[i] * inv);
        p1[i] = f2b(o[8 + i] * inv);
    }
    *(short8v*)dst = p0;
    *(short8v*)(dst + 8) = p1;
}

// ---------------------------------------------------------------------------
// LayerNorm over 512, one wave per row, in-place; optional bf16 copy out.
// ---------------------------------------------------------------------------
__global__ __launch_bounds__(64) void ln_kernel(float* __restrict__ X,
                                                const float* __restrict__ g,
                                                const float* __restrict__ b,
                                                unsigned short* __restrict__ Xb)
{
    const size_t row = blockIdx.x;
    const int t = threadIdx.x;
    float* xr = X + row * DMODEL;
    f32x4 x0 = *(const f32x4*)&xr[t * 4];
    f32x4 x1 = *(const f32x4*)&xr[256 + t * 4];

    float s  = x0[0] + x0[1] + x0[2] + x0[3] + x1[0] + x1[1] + x1[2] + x1[3];
    float sq = x0[0]*x0[0] + x0[1]*x0[1] + x0[2]*x0[2] + x0[3]*x0[3] +
               x1[0]*x1[0] + x1[1]*x1[1] + x1[2]*x1[2] + x1[3]*x1[3];
#pragma unroll
    for (int m = 1; m < 64; m <<= 1) {
        s  += __shfl_xor(s, m);
        sq += __shfl_xor(sq, m);
    }
    const float mu  = s * (1.f / DMODEL);
    const float var = sq * (1.f / DMODEL) - mu * mu;
    const float rr  = rsqrtf(var + LN_EPS);

    const int c0 = t * 4, c1 = 256 + t * 4;
    f32x4 g0 = *(const f32x4*)&g[c0], g1v = *(const f32x4*)&g[c1];
    f32x4 b0 = *(const f32x4*)&b[c0], b1v = *(const f32x4*)&b[c1];
    f32x4 y0, y1;
#pragma unroll
    for (int i = 0; i < 4; ++i) {
        y0[i] = (x0[i] - mu) * rr * g0[i] + b0[i];
        y1[i] = (x1[i] - mu) * rr * g1v[i] + b1v[i];
    }
    *(f32x4*)&xr[c0] = y0;
    *(f32x4*)&xr[c1] = y1;
    if (Xb) {
        unsigned short* xb = Xb + row * DMODEL;
        ushort4 u0, u1;
        u0.x = f2b(y0[0]); u0.y = f2b(y0[1]); u0.z = f2b(y0[2]); u0.w = f2b(y0[3]);
        u1.x = f2b(y1[0]); u1.y = f2b(y1[1]); u1.z = f2b(y1[2]); u1.w = f2b(y1[3]);
        *(ushort4*)&xb[c0] = u0;
        *(ushort4*)&xb[c1] = u1;
    }
}

// ---------------------------------------------------------------------------
extern "C" void kernel_launch(void* const* d_in, const int* in_sizes, int n_in,
                              void* d_out, int out_size, void* d_ws, size_t ws_size,
                              hipStream_t stream)
{
    const float* h   = (const float*)d_in[0];
    const float* Wq  = (const float*)d_in[1];
    const float* bq  = (const float*)d_in[2];
    const float* Wk  = (const float*)d_in[3];
    const float* bk  = (const float*)d_in[4];
    const float* Wv  = (const float*)d_in[5];
    const float* bv  = (const float*)d_in[6];
    const float* Wo  = (const float*)d_in[7];
    const float* bo  = (const float*)d_in[8];
    const float* W1  = (const float*)d_in[9];
    const float* b1  = (const float*)d_in[10];
    const float* W2  = (const float*)d_in[11];
    const float* b2  = (const float*)d_in[12];
    const float* g1  = (const float*)d_in[13];
    const float* be1 = (const float*)d_in[14];
    const float* g2  = (const float*)d_in[15];
    const float* be2 = (const float*)d_in[16];
    const float* gf  = (const float*)d_in[17];
    const float* bef = (const float*)d_in[18];

    float* x = (float*)d_out;                     // running activation f32 [8192,512]
    char* ws = (char*)d_ws;
    const size_t MB = 1024 * 1024;
    unsigned short* x_bf = (unsigned short*)(ws);                 // 8 MB
    unsigned short* qkv  = (unsigned short*)(ws + 8 * MB);        // q|k|v 24 MB
    unsigned short* qb   = qkv;
    unsigned short* kb   = qkv + SEGSTRIDE;
    unsigned short* vb   = qkv + 2 * (size_t)SEGSTRIDE;
    unsigned short* ab   = (unsigned short*)(ws + 32 * MB);       // 8 MB
    unsigned short* hid  = (unsigned short*)(ws + 8 * MB);        // 32 MB alias q|k|v|a
    float* KVp = (float*)(ws + 40 * MB);                          // 16 MB
    float* zp  = (float*)(ws + 56 * MB);                          // 0.5 MB
    unsigned short* WTall = (unsigned short*)(ws + 57 * MB);      // 24 MB

    const int M = MROWS, D = DMODEL, DF = DFF;
    const size_t LSTR = 3 * 1024 * 1024;  // elems per layer in WTall (3,145,728)

    // setup: input convert + weight transposes
    cvt_in<<<dim3(M * D / (256 * 8)), 256, 0, stream>>>(h, x, x_bf, M * D);
    for (int l = 0; l < LAYERS; ++l) {
        unsigned short* WL = WTall + (size_t)l * LSTR;
        transpose_to_bf16<<<dim3(D / 32, D / 32), 256, 0, stream>>>(Wq + (size_t)l * D * D, WL, D, D);
        transpose_to_bf16<<<dim3(D / 32, D / 32), 256, 0, stream>>>(Wk + (size_t)l * D * D, WL + 262144, D, D);
        transpose_to_bf16<<<dim3(D / 32, D / 32), 256, 0, stream>>>(Wv + (size_t)l * D * D, WL + 524288, D, D);
        transpose_to_bf16<<<dim3(D / 32, D / 32), 256, 0, stream>>>(Wo + (size_t)l * D * D, WL + 786432, D, D);
        transpose_to_bf16<<<dim3(D / 32, DF / 32), 256, 0, stream>>>(W1 + (size_t)l * D * DF, WL + 1048576, D, DF);
        transpose_to_bf16<<<dim3(DF / 32, D / 32), 256, 0, stream>>>(W2 + (size_t)l * DF * D, WL + 2097152, DF, D);
    }

    for (int l = 0; l < LAYERS; ++l) {
        unsigned short* WL = WTall + (size_t)l * LSTR;
        const unsigned short* WqkvT = WL;            // [1536][512]
        const unsigned short* WoT   = WL + 786432;   // [512][512]
        const unsigned short* W1T   = WL + 1048576;  // [2048][512]
        const unsigned short* W2T   = WL + 2097152;  // [512][2048]

        // fused q|k|v projection GEMM (elu+1 on q,k), bf16 out
        gemm_bf16<3, false, false, true><<<dim3(M / 128, 1536 / 128), 256, 0, stream>>>(
            x_bf, WqkvT, bq + (size_t)l * D, bk + (size_t)l * D, bv + (size_t)l * D,
            nullptr, qkv, M, 1536, D);

        // chunked causal linear attention
        attn_stage1<<<dim3(NCHUNK, NH, NB), 256, 0, stream>>>(kb, vb, KVp, zp);
        attn_stage2<<<dim3(NB * NH), 256, 0, stream>>>(KVp, zp);
        attn_stage3<<<dim3(NCHUNK, NH, NB), 256, 0, stream>>>(qb, kb, vb, KVp, zp, ab);

        // out projection + residual into x (f32), then LN1 (writes x + x_bf)
        gemm_bf16<0, true, true, false><<<dim3(M / 128, D / 128), 256, 0, stream>>>(
            ab, WoT, bo + (size_t)l * D, nullptr, nullptr, x, nullptr, M, D, D);
        ln_kernel<<<dim3(M), 64, 0, stream>>>(x, g1 + (size_t)l * D, be1 + (size_t)l * D, x_bf);

        // FFN
        gemm_bf16<2, false, false, true><<<dim3(M / 128, DF / 128), 256, 0, stream>>>(
            x_bf, W1T, b1 + (size_t)l * DF, nullptr, nullptr, nullptr, hid, M, DF, D);
        gemm_bf16<0, true, true, false><<<dim3(M / 128, D / 128), 256, 0, stream>>>(
            hid, W2T, b2 + (size_t)l * D, nullptr, nullptr, x, nullptr, M, D, DF);
        ln_kernel<<<dim3(M), 64, 0, stream>>>(x, g2 + (size_t)l * D, be2 + (size_t)l * D, x_bf);
    }

    ln_kernel<<<dim3(M), 64, 0, stream>>>(x, gf, bef, nullptr);
}

// Round 3
// 1223.469 us; speedup vs baseline: 3.1230x; 1.0787x over previous
//
#include <hip/hip_runtime.h>
#include <hip/hip_bf16.h>
#include <math.h>

#define LAYERS 4
#define DMODEL 512
#define NH 8
#define DH 64
#define DFF 2048
#define NB 4
#define S_LEN 2048
#define MROWS 8192
#define CHUNK 64
#define NCHUNK 32            // S_LEN / CHUNK
#define ATT_EPS 1e-6f
#define LN_EPS 1e-5f
#define SEGSTRIDE (MROWS * DMODEL)   // 4194304 elems per q/k/v segment

typedef __attribute__((ext_vector_type(8))) short short8v;   // 8 bf16
typedef __attribute__((ext_vector_type(4))) float f32x4;

__device__ __forceinline__ float b2f(unsigned short u) {
    union { float f; unsigned u; } c; c.u = ((unsigned)u) << 16; return c.f;
}
__device__ __forceinline__ unsigned short f2b(float f) {
    union { float f; unsigned u; } c; c.f = f;
    unsigned r = c.u + 0x7FFFu + ((c.u >> 16) & 1u);
    return (unsigned short)(r >> 16);
}
__device__ __forceinline__ void gload16(const void* g, void* l) {
    __builtin_amdgcn_global_load_lds(
        (const __attribute__((address_space(1))) void*)g,
        (__attribute__((address_space(3))) void*)l, 16, 0, 0);
}
__device__ __forceinline__ float elu1f(float v) {
    return (v > 0.f) ? (v + 1.f) : __expf(v);
}
__device__ __forceinline__ float geluf(float v) {
    // tanh-form GELU, |err vs exact erf-GELU| <= ~1e-3
    float u = 0.7978845608028654f * v * (1.f + 0.044715f * v * v);
    float th = 1.f - 2.f / (1.f + __expf(2.f * u));
    return 0.5f * v * (1.f + th);
}

// ---------------------------------------------------------------------------
// bf16 MFMA GEMM: C[M,N] = act(A[M,K] @ W[K,N] + bias) (+C32 if ACCUM)
// A: bf16 row-major [M][K]. WT: bf16 [N][K] (W transposed).
// ACT: 0=none, 1=elu+1, 2=gelu, 3=qkv-fused (col segs of 512: seg<2 elu+1)
// 128x128 tile, BK=32, 256 threads (4 waves, 2x2), 16x16x32 MFMA.
// 2-phase LDS double-buffer + bank-conflict swizzle (source+read, linear dest).
// ---------------------------------------------------------------------------
template <int ACT, bool ACCUM, bool WF32, bool WBF16>
__global__ __launch_bounds__(256) void gemm_bf16(
    const unsigned short* __restrict__ A,
    const unsigned short* __restrict__ WT,
    const float* __restrict__ b0, const float* __restrict__ b1,
    const float* __restrict__ b2,
    float* __restrict__ C32, unsigned short* __restrict__ Cbf,
    int M, int N, int K)
{
    __shared__ short As[2][4096];
    __shared__ short Bs[2][4096];

    const int t = threadIdx.x;
    const int m0 = blockIdx.x * 128, n0 = blockIdx.y * 128;
    const int lane = t & 63, wid = t >> 6;
    const int wm = (wid >> 1) * 64, wn = (wid & 1) * 64;
    const int fr = lane & 15, kg = lane >> 4;

    // staging: LDS 16B-unit u holds (row=u>>2, kslot=(u&3)^s(row)),
    // s(r) = (r&3)^((r>>2)&3). Linear LDS dest (gload_lds), swizzled source.
    const int srow = t >> 2;                          // 0..63
    const int ssw  = (srow & 3) ^ ((srow >> 2) & 3);
    const int sk   = ((t & 3) ^ ssw) * 8;             // swizzled k-offset (shorts)

    // read-side swizzle: for fragment row wm+m*16+fr, s(row) depends only on fr
    const int rsw  = (fr & 3) ^ ((fr >> 2) & 3);
    const int kgs  = (kg ^ rsw) * 8;

    const unsigned short* Ar0 = A + (size_t)(m0 + srow) * K + sk;
    const unsigned short* Ar1 = A + (size_t)(m0 + srow + 64) * K + sk;
    const unsigned short* Br0 = WT + (size_t)(n0 + srow) * K + sk;
    const unsigned short* Br1 = WT + (size_t)(n0 + srow + 64) * K + sk;

    f32x4 acc[4][4];
#pragma unroll
    for (int m = 0; m < 4; ++m)
#pragma unroll
        for (int n = 0; n < 4; ++n) acc[m][n] = (f32x4){0.f, 0.f, 0.f, 0.f};

#define STAGE(buf, kk) do {                              \
    gload16(Ar0 + (kk), &As[buf][t * 8]);                \
    gload16(Ar1 + (kk), &As[buf][t * 8 + 2048]);         \
    gload16(Br0 + (kk), &Bs[buf][t * 8]);                \
    gload16(Br1 + (kk), &Bs[buf][t * 8 + 2048]); } while (0)

    const int NT = K >> 5;
    STAGE(0, 0);
    __syncthreads();

    int cur = 0;
    for (int td = 0; td < NT; ++td) {
        if (td + 1 < NT) STAGE(cur ^ 1, (td + 1) * 32);  // prefetch next tile

        short8v a[4], b[4];
#pragma unroll
        for (int m = 0; m < 4; ++m)
            a[m] = *(const short8v*)&As[cur][(wm + m * 16 + fr) * 32 + kgs];
#pragma unroll
        for (int n = 0; n < 4; ++n)
            b[n] = *(const short8v*)&Bs[cur][(wn + n * 16 + fr) * 32 + kgs];
#pragma unroll
        for (int m = 0; m < 4; ++m)
#pragma unroll
            for (int n = 0; n < 4; ++n)
                acc[m][n] = __builtin_amdgcn_mfma_f32_16x16x32_bf16(
                    a[m], b[n], acc[m][n], 0, 0, 0);

        __syncthreads();   // drains prefetch vmcnt; latency hidden under MFMA
        cur ^= 1;
    }
#undef STAGE

    // epilogue
    const int seg = (ACT == 3) ? (n0 >> 9) : 0;
    const float* bias = (ACT == 3) ? (seg == 0 ? b0 : (seg == 1 ? b1 : b2)) : b0;
    float bv[4];
#pragma unroll
    for (int n = 0; n < 4; ++n) {
        const int col = n0 + wn + n * 16 + fr;
        bv[n] = bias[(ACT == 3) ? (col - seg * 512) : col];
    }

#pragma unroll
    for (int m = 0; m < 4; ++m)
#pragma unroll
        for (int n = 0; n < 4; ++n)
#pragma unroll
            for (int j = 0; j < 4; ++j) {
                const int row = m0 + wm + m * 16 + (lane >> 4) * 4 + j;
                const int col = n0 + wn + n * 16 + fr;
                float v = acc[m][n][j] + bv[n];
                if (ACCUM) v += C32[(size_t)row * N + col];
                if (ACT == 1) v = elu1f(v);
                else if (ACT == 2) v = geluf(v);
                else if (ACT == 3) { if (seg < 2) v = elu1f(v); }
                if (WF32) C32[(size_t)row * N + col] = v;
                if (WBF16) {
                    if (ACT == 3)
                        Cbf[(size_t)seg * SEGSTRIDE + (size_t)row * 512 + (col - seg * 512)] = f2b(v);
                    else
                        Cbf[(size_t)row * N + col] = f2b(v);
                }
            }
}

// ---------------------------------------------------------------------------
// Weight transpose + bf16: W [K][N] f32 -> WT [N][K] bf16
// ---------------------------------------------------------------------------
__global__ __launch_bounds__(256) void transpose_to_bf16(
    const float* __restrict__ W, unsigned short* __restrict__ WT, int K, int N)
{
    __shared__ float tile[32][33];
    const int k0 = blockIdx.x * 32, n0 = blockIdx.y * 32;
    const int tx = threadIdx.x & 31, ty = threadIdx.x >> 5;
#pragma unroll
    for (int i = ty; i < 32; i += 8)
        tile[i][tx] = W[(size_t)(k0 + i) * N + n0 + tx];
    __syncthreads();
#pragma unroll
    for (int i = ty; i < 32; i += 8)
        WT[(size_t)(n0 + i) * K + k0 + tx] = f2b(tile[tx][i]);
}

// ---------------------------------------------------------------------------
// input convert: h f32 -> x f32 copy + xb bf16
// ---------------------------------------------------------------------------
__global__ __launch_bounds__(256) void cvt_in(
    const float* __restrict__ h, float* __restrict__ x,
    unsigned short* __restrict__ xb, int n)
{
    const int i = (blockIdx.x * 256 + threadIdx.x) * 8;
    if (i >= n) return;
    f32x4 a = *(const f32x4*)(h + i);
    f32x4 b = *(const f32x4*)(h + i + 4);
    *(f32x4*)(x + i) = a;
    *(f32x4*)(x + i + 4) = b;
    short8v p;
    p[0] = f2b(a[0]); p[1] = f2b(a[1]); p[2] = f2b(a[2]); p[3] = f2b(a[3]);
    p[4] = f2b(b[0]); p[5] = f2b(b[1]); p[6] = f2b(b[2]); p[7] = f2b(b[3]);
    *(short8v*)(xb + i) = p;
}

// ---------------------------------------------------------------------------
// Attention stage 1: per (b,h,chunk of 64) states KV = K^T V, z = colsum K
// ---------------------------------------------------------------------------
__global__ __launch_bounds__(256) void attn_stage1(
    const unsigned short* __restrict__ Kf, const unsigned short* __restrict__ Vf,
    float* __restrict__ KVp, float* __restrict__ zp)
{
    const int c = blockIdx.x, hh = blockIdx.y, bb = blockIdx.z;
    const int t = threadIdx.x;
    __shared__ float Ks[CHUNK][68];
    __shared__ float Vs[CHUNK][68];

    const size_t rowbase = (size_t)(bb * S_LEN + c * CHUNK);
    const int colbase = hh * DH;
    const int r = t >> 2, cs = (t & 3) * 16;
    {
        const unsigned short* kp = Kf + (rowbase + r) * DMODEL + colbase + cs;
        const unsigned short* vp = Vf + (rowbase + r) * DMODEL + colbase + cs;
        short8v k0 = *(const short8v*)kp, k1 = *(const short8v*)(kp + 8);
        short8v v0 = *(const short8v*)vp, v1 = *(const short8v*)(vp + 8);
#pragma unroll
        for (int i = 0; i < 8; ++i) {
            Ks[r][cs + i] = b2f((unsigned short)k0[i]);
            Ks[r][cs + 8 + i] = b2f((unsigned short)k1[i]);
            Vs[r][cs + i] = b2f((unsigned short)v0[i]);
            Vs[r][cs + 8 + i] = b2f((unsigned short)v1[i]);
        }
    }
    __syncthreads();

    const int d = t >> 2, e0 = (t & 3) * 16;
    float acc[16];
#pragma unroll
    for (int i = 0; i < 16; ++i) acc[i] = 0.f;
    for (int j = 0; j < CHUNK; ++j) {
        const float kd = Ks[j][d];
#pragma unroll
        for (int i = 0; i < 16; ++i) acc[i] += kd * Vs[j][e0 + i];
    }
    float* dst = KVp + ((size_t)((bb * NH + hh) * NCHUNK + c)) * (DH * DH) + d * DH + e0;
#pragma unroll
    for (int i = 0; i < 16; i += 4)
        *(f32x4*)(dst + i) = (f32x4){acc[i], acc[i + 1], acc[i + 2], acc[i + 3]};

    if (t < DH) {
        float s = 0.f;
        for (int j = 0; j < CHUNK; ++j) s += Ks[j][t];
        zp[((size_t)(bb * NH + hh) * NCHUNK + c) * DH + t] = s;
    }
}

// ---------------------------------------------------------------------------
// Attention stage 2: exclusive prefix over 32 chunk states per (b,h)
// ---------------------------------------------------------------------------
__global__ __launch_bounds__(256) void attn_stage2(float* __restrict__ KVp,
                                                   float* __restrict__ zp)
{
    const int bh = blockIdx.x;
    const int t = threadIdx.x;
    for (int e = t; e < DH * DH; e += 256) {
        float run = 0.f;
        const size_t base = (size_t)bh * NCHUNK * DH * DH + e;
#pragma unroll 4
        for (int c = 0; c < NCHUNK; ++c) {
            const float tmp = KVp[base + (size_t)c * DH * DH];
            KVp[base + (size_t)c * DH * DH] = run;
            run += tmp;
        }
    }
    if (t < DH) {
        float run = 0.f;
        const size_t base = (size_t)bh * NCHUNK * DH + t;
#pragma unroll 4
        for (int c = 0; c < NCHUNK; ++c) {
            const float tmp = zp[base + c * DH];
            zp[base + c * DH] = run;
            run += tmp;
        }
    }
}

// ---------------------------------------------------------------------------
// Attention stage 3: 256 threads = 64 rows x 4 e-slices of 16.
// out_i = (q_i@KV_pre + sum_{j<=i} s_ij v_j) / (q_i@z_pre + sum_{j<=i} s_ij + eps)
// ---------------------------------------------------------------------------
__global__ __launch_bounds__(256) void attn_stage3(
    const unsigned short* __restrict__ Qf, const unsigned short* __restrict__ Kf,
    const unsigned short* __restrict__ Vf, const float* __restrict__ KVp,
    const float* __restrict__ zp, unsigned short* __restrict__ Af)
{
    const int c = blockIdx.x, hh = blockIdx.y, bb = blockIdx.z;
    const int t = threadIdx.x;
    const int r = t >> 2, eg = t & 3, e0 = eg * 16, wid = t >> 6;

    __shared__ float Ksf[CHUNK][68];
    __shared__ float Vsf[CHUNK][68];
    __shared__ float KVs[DH * DH];
    __shared__ float zsh[DH];

    const size_t rowbase = (size_t)(bb * S_LEN + c * CHUNK);
    const int colbase = hh * DH;

    {   // K, V chunk -> LDS (f32)
        const int cs = (t & 3) * 16;
        const unsigned short* kp = Kf + (rowbase + r) * DMODEL + colbase + cs;
        const unsigned short* vp = Vf + (rowbase + r) * DMODEL + colbase + cs;
        short8v k0 = *(const short8v*)kp, k1 = *(const short8v*)(kp + 8);
        short8v v0 = *(const short8v*)vp, v1 = *(const short8v*)(vp + 8);
#pragma unroll
        for (int i = 0; i < 8; ++i) {
            Ksf[r][cs + i] = b2f((unsigned short)k0[i]);
            Ksf[r][cs + 8 + i] = b2f((unsigned short)k1[i]);
            Vsf[r][cs + i] = b2f((unsigned short)v0[i]);
            Vsf[r][cs + 8 + i] = b2f((unsigned short)v1[i]);
        }
    }
    {   // KV_pre, z_pre -> LDS
        const float* kvsrc = KVp + ((size_t)((bb * NH + hh) * NCHUNK + c)) * (DH * DH);
#pragma unroll
        for (int e = t * 4; e < DH * DH; e += 1024)
            *(f32x4*)&KVs[e] = *(const f32x4*)&kvsrc[e];
        if (t < DH)
            zsh[t] = zp[((size_t)(bb * NH + hh) * NCHUNK + c) * DH + t];
    }
    // q row -> registers
    float q[DH];
    {
        const unsigned short* qp = Qf + (rowbase + r) * DMODEL + colbase;
#pragma unroll
        for (int d = 0; d < DH; d += 8) {
            short8v qv = *(const short8v*)(qp + d);
#pragma unroll
            for (int i = 0; i < 8; ++i) q[d + i] = b2f((unsigned short)qv[i]);
        }
    }
    __syncthreads();

    float o[16];
#pragma unroll
    for (int i = 0; i < 16; ++i) o[i] = 0.f;
    float den = 0.f;

    // o += q @ KV_pre (own e-slice); den += q . z_pre
#pragma unroll
    for (int d = 0; d < DH; ++d) {
        const float qd = q[d];
        const float* kvr = &KVs[d * DH + e0];
#pragma unroll
        for (int i = 0; i < 16; i += 4) {
            f32x4 kv = *(const f32x4*)(kvr + i);
            o[i + 0] += qd * kv[0];
            o[i + 1] += qd * kv[1];
            o[i + 2] += qd * kv[2];
            o[i + 3] += qd * kv[3];
        }
        den += qd * zsh[d];
    }

    // intra-chunk causal part; wave-uniform early exit at jmax
    const int jmax = wid * 16 + 15;
    for (int j = 0; j <= jmax; ++j) {
        float s = 0.f;
#pragma unroll
        for (int d = 0; d < DH; d += 4) {
            f32x4 kk = *(const f32x4*)&Ksf[j][d];
            s += q[d] * kk[0] + q[d + 1] * kk[1] + q[d + 2] * kk[2] + q[d + 3] * kk[3];
        }
        if (j <= r) {
            den += s;
            const float* vr = &Vsf[j][e0];
#pragma unroll
            for (int i = 0; i < 16; ++i) o[i] += s * vr[i];
        }
    }

    const float inv = 1.f / (den + ATT_EPS);
    unsigned short* dst = Af + (rowbase + r) * DMODEL + colbase + e0;
    short8v p0, p1;
#pragma unroll
    for (int i = 0; i < 8; ++i) {
        p0[i] = f2b(o[i] * inv);
        p1[i] = f2b(o[8 + i] * inv);
    }
    *(short8v*)dst = p0;
    *(short8v*)(dst + 8) = p1;
}

// ---------------------------------------------------------------------------
// LayerNorm over 512: 4 rows per block (one wave each), in-place; bf16 copy.
// ---------------------------------------------------------------------------
__global__ __launch_bounds__(256) void ln_kernel(float* __restrict__ X,
                                                 const float* __restrict__ g,
                                                 const float* __restrict__ b,
                                                 unsigned short* __restrict__ Xb)
{
    const size_t row = blockIdx.x * 4 + (threadIdx.x >> 6);
    const int t = threadIdx.x & 63;
    float* xr = X + row * DMODEL;
    f32x4 x0 = *(const f32x4*)&xr[t * 4];
    f32x4 x1 = *(const f32x4*)&xr[256 + t * 4];

    float s  = x0[0] + x0[1] + x0[2] + x0[3] + x1[0] + x1[1] + x1[2] + x1[3];
    float sq = x0[0]*x0[0] + x0[1]*x0[1] + x0[2]*x0[2] + x0[3]*x0[3] +
               x1[0]*x1[0] + x1[1]*x1[1] + x1[2]*x1[2] + x1[3]*x1[3];
#pragma unroll
    for (int m = 1; m < 64; m <<= 1) {
        s  += __shfl_xor(s, m);
        sq += __shfl_xor(sq, m);
    }
    const float mu  = s * (1.f / DMODEL);
    const float var = sq * (1.f / DMODEL) - mu * mu;
    const float rr  = rsqrtf(var + LN_EPS);

    const int c0 = t * 4, c1 = 256 + t * 4;
    f32x4 g0 = *(const f32x4*)&g[c0], g1v = *(const f32x4*)&g[c1];
    f32x4 b0 = *(const f32x4*)&b[c0], b1v = *(const f32x4*)&b[c1];
    f32x4 y0, y1;
#pragma unroll
    for (int i = 0; i < 4; ++i) {
        y0[i] = (x0[i] - mu) * rr * g0[i] + b0[i];
        y1[i] = (x1[i] - mu) * rr * g1v[i] + b1v[i];
    }
    *(f32x4*)&xr[c0] = y0;
    *(f32x4*)&xr[c1] = y1;
    if (Xb) {
        unsigned short* xb = Xb + row * DMODEL;
        ushort4 u0, u1;
        u0.x = f2b(y0[0]); u0.y = f2b(y0[1]); u0.z = f2b(y0[2]); u0.w = f2b(y0[3]);
        u1.x = f2b(y1[0]); u1.y = f2b(y1[1]); u1.z = f2b(y1[2]); u1.w = f2b(y1[3]);
        *(ushort4*)&xb[c0] = u0;
        *(ushort4*)&xb[c1] = u1;
    }
}

// ---------------------------------------------------------------------------
extern "C" void kernel_launch(void* const* d_in, const int* in_sizes, int n_in,
                              void* d_out, int out_size, void* d_ws, size_t ws_size,
                              hipStream_t stream)
{
    const float* h   = (const float*)d_in[0];
    const float* Wq  = (const float*)d_in[1];
    const float* bq  = (const float*)d_in[2];
    const float* Wk  = (const float*)d_in[3];
    const float* bk  = (const float*)d_in[4];
    const float* Wv  = (const float*)d_in[5];
    const float* bv  = (const float*)d_in[6];
    const float* Wo  = (const float*)d_in[7];
    const float* bo  = (const float*)d_in[8];
    const float* W1  = (const float*)d_in[9];
    const float* b1  = (const float*)d_in[10];
    const float* W2  = (const float*)d_in[11];
    const float* b2  = (const float*)d_in[12];
    const float* g1  = (const float*)d_in[13];
    const float* be1 = (const float*)d_in[14];
    const float* g2  = (const float*)d_in[15];
    const float* be2 = (const float*)d_in[16];
    const float* gf  = (const float*)d_in[17];
    const float* bef = (const float*)d_in[18];

    float* x = (float*)d_out;                     // running activation f32 [8192,512]
    char* ws = (char*)d_ws;
    const size_t MB = 1024 * 1024;
    unsigned short* x_bf = (unsigned short*)(ws);                 // 8 MB
    unsigned short* qkv  = (unsigned short*)(ws + 8 * MB);        // q|k|v 24 MB
    unsigned short* qb   = qkv;
    unsigned short* kb   = qkv + SEGSTRIDE;
    unsigned short* vb   = qkv + 2 * (size_t)SEGSTRIDE;
    unsigned short* ab   = (unsigned short*)(ws + 32 * MB);       // 8 MB
    unsigned short* hid  = (unsigned short*)(ws + 8 * MB);        // 32 MB alias q|k|v|a
    float* KVp = (float*)(ws + 40 * MB);                          // 16 MB
    float* zp  = (float*)(ws + 56 * MB);                          // 0.5 MB
    unsigned short* WTall = (unsigned short*)(ws + 57 * MB);      // 24 MB

    const int M = MROWS, D = DMODEL, DF = DFF;
    const size_t LSTR = 3 * 1024 * 1024;  // elems per layer in WTall

    // setup: input convert + weight transposes
    cvt_in<<<dim3(M * D / (256 * 8)), 256, 0, stream>>>(h, x, x_bf, M * D);
    for (int l = 0; l < LAYERS; ++l) {
        unsigned short* WL = WTall + (size_t)l * LSTR;
        transpose_to_bf16<<<dim3(D / 32, D / 32), 256, 0, stream>>>(Wq + (size_t)l * D * D, WL, D, D);
        transpose_to_bf16<<<dim3(D / 32, D / 32), 256, 0, stream>>>(Wk + (size_t)l * D * D, WL + 262144, D, D);
        transpose_to_bf16<<<dim3(D / 32, D / 32), 256, 0, stream>>>(Wv + (size_t)l * D * D, WL + 524288, D, D);
        transpose_to_bf16<<<dim3(D / 32, D / 32), 256, 0, stream>>>(Wo + (size_t)l * D * D, WL + 786432, D, D);
        transpose_to_bf16<<<dim3(D / 32, DF / 32), 256, 0, stream>>>(W1 + (size_t)l * D * DF, WL + 1048576, D, DF);
        transpose_to_bf16<<<dim3(DF / 32, D / 32), 256, 0, stream>>>(W2 + (size_t)l * DF * D, WL + 2097152, DF, D);
    }

    for (int l = 0; l < LAYERS; ++l) {
        unsigned short* WL = WTall + (size_t)l * LSTR;
        const unsigned short* WqkvT = WL;            // [1536][512]
        const unsigned short* WoT   = WL + 786432;   // [512][512]
        const unsigned short* W1T   = WL + 1048576;  // [2048][512]
        const unsigned short* W2T   = WL + 2097152;  // [512][2048]

        // fused q|k|v projection GEMM (elu+1 on q,k), bf16 out
        gemm_bf16<3, false, false, true><<<dim3(M / 128, 1536 / 128), 256, 0, stream>>>(
            x_bf, WqkvT, bq + (size_t)l * D, bk + (size_t)l * D, bv + (size_t)l * D,
            nullptr, qkv, M, 1536, D);

        // chunked causal linear attention
        attn_stage1<<<dim3(NCHUNK, NH, NB), 256, 0, stream>>>(kb, vb, KVp, zp);
        attn_stage2<<<dim3(NB * NH), 256, 0, stream>>>(KVp, zp);
        attn_stage3<<<dim3(NCHUNK, NH, NB), 256, 0, stream>>>(qb, kb, vb, KVp, zp, ab);

        // out projection + residual into x (f32), then LN1 (writes x + x_bf)
        gemm_bf16<0, true, true, false><<<dim3(M / 128, D / 128), 256, 0, stream>>>(
            ab, WoT, bo + (size_t)l * D, nullptr, nullptr, x, nullptr, M, D, D);
        ln_kernel<<<dim3(M / 4), 256, 0, stream>>>(x, g1 + (size_t)l * D, be1 + (size_t)l * D, x_bf);

        // FFN
        gemm_bf16<2, false, false, true><<<dim3(M / 128, DF / 128), 256, 0, stream>>>(
            x_bf, W1T, b1 + (size_t)l * DF, nullptr, nullptr, nullptr, hid, M, DF, D);
        gemm_bf16<0, true, true, false><<<dim3(M / 128, D / 128), 256, 0, stream>>>(
            hid, W2T, b2 + (size_t)l * D, nullptr, nullptr, x, nullptr, M, D, DF);
        ln_kernel<<<dim3(M / 4), 256, 0, stream>>>(x, g2 + (size_t)l * D, be2 + (size_t)l * D, x_bf);
    }

    ln_kernel<<<dim3(M / 4), 256, 0, stream>>>(x, gf, bef, nullptr);
}

// Round 4
// 800.232 us; speedup vs baseline: 4.7747x; 1.5289x over previous
//
#include <hip/hip_runtime.h>
#include <hip/hip_bf16.h>
#include <math.h>

#define LAYERS 4
#define DMODEL 512
#define NH 8
#define DH 64
#define DFF 2048
#define NB 4
#define S_LEN 2048
#define MROWS 8192
#define CHUNK 64
#define NCHUNK 32            // S_LEN / CHUNK
#define ATT_EPS 1e-6f
#define LN_EPS 1e-5f
#define SEGSTRIDE (MROWS * DMODEL)   // 4194304 elems per q/k/v segment

typedef __attribute__((ext_vector_type(8))) short short8v;   // 8 bf16
typedef __attribute__((ext_vector_type(4))) float f32x4;

__device__ __forceinline__ float b2f(unsigned short u) {
    union { float f; unsigned u; } c; c.u = ((unsigned)u) << 16; return c.f;
}
__device__ __forceinline__ unsigned short f2b(float f) {
    union { float f; unsigned u; } c; c.f = f;
    unsigned r = c.u + 0x7FFFu + ((c.u >> 16) & 1u);
    return (unsigned short)(r >> 16);
}
__device__ __forceinline__ void gload16(const void* g, void* l) {
    __builtin_amdgcn_global_load_lds(
        (const __attribute__((address_space(1))) void*)g,
        (__attribute__((address_space(3))) void*)l, 16, 0, 0);
}
__device__ __forceinline__ float elu1f(float v) {
    return (v > 0.f) ? (v + 1.f) : __expf(v);
}
__device__ __forceinline__ float geluf(float v) {
    float u = 0.7978845608028654f * v * (1.f + 0.044715f * v * v);
    float th = 1.f - 2.f / (1.f + __expf(2.f * u));
    return 0.5f * v * (1.f + th);
}

// ---------------------------------------------------------------------------
// bf16 MFMA GEMM (unchanged from R3): 128x128 tile, BK=32, 2-phase dbuf+swizzle
// ---------------------------------------------------------------------------
template <int ACT, bool ACCUM, bool WF32, bool WBF16>
__global__ __launch_bounds__(256) void gemm_bf16(
    const unsigned short* __restrict__ A,
    const unsigned short* __restrict__ WT,
    const float* __restrict__ b0, const float* __restrict__ b1,
    const float* __restrict__ b2,
    float* __restrict__ C32, unsigned short* __restrict__ Cbf,
    int M, int N, int K)
{
    __shared__ short As[2][4096];
    __shared__ short Bs[2][4096];

    const int t = threadIdx.x;
    const int m0 = blockIdx.x * 128, n0 = blockIdx.y * 128;
    const int lane = t & 63, wid = t >> 6;
    const int wm = (wid >> 1) * 64, wn = (wid & 1) * 64;
    const int fr = lane & 15, kg = lane >> 4;

    const int srow = t >> 2;
    const int ssw  = (srow & 3) ^ ((srow >> 2) & 3);
    const int sk   = ((t & 3) ^ ssw) * 8;

    const int rsw  = (fr & 3) ^ ((fr >> 2) & 3);
    const int kgs  = (kg ^ rsw) * 8;

    const unsigned short* Ar0 = A + (size_t)(m0 + srow) * K + sk;
    const unsigned short* Ar1 = A + (size_t)(m0 + srow + 64) * K + sk;
    const unsigned short* Br0 = WT + (size_t)(n0 + srow) * K + sk;
    const unsigned short* Br1 = WT + (size_t)(n0 + srow + 64) * K + sk;

    f32x4 acc[4][4];
#pragma unroll
    for (int m = 0; m < 4; ++m)
#pragma unroll
        for (int n = 0; n < 4; ++n) acc[m][n] = (f32x4){0.f, 0.f, 0.f, 0.f};

#define STAGE(buf, kk) do {                              \
    gload16(Ar0 + (kk), &As[buf][t * 8]);                \
    gload16(Ar1 + (kk), &As[buf][t * 8 + 2048]);         \
    gload16(Br0 + (kk), &Bs[buf][t * 8]);                \
    gload16(Br1 + (kk), &Bs[buf][t * 8 + 2048]); } while (0)

    const int NT = K >> 5;
    STAGE(0, 0);
    __syncthreads();

    int cur = 0;
    for (int td = 0; td < NT; ++td) {
        if (td + 1 < NT) STAGE(cur ^ 1, (td + 1) * 32);

        short8v a[4], b[4];
#pragma unroll
        for (int m = 0; m < 4; ++m)
            a[m] = *(const short8v*)&As[cur][(wm + m * 16 + fr) * 32 + kgs];
#pragma unroll
        for (int n = 0; n < 4; ++n)
            b[n] = *(const short8v*)&Bs[cur][(wn + n * 16 + fr) * 32 + kgs];
#pragma unroll
        for (int m = 0; m < 4; ++m)
#pragma unroll
            for (int n = 0; n < 4; ++n)
                acc[m][n] = __builtin_amdgcn_mfma_f32_16x16x32_bf16(
                    a[m], b[n], acc[m][n], 0, 0, 0);

        __syncthreads();
        cur ^= 1;
    }
#undef STAGE

    const int seg = (ACT == 3) ? (n0 >> 9) : 0;
    const float* bias = (ACT == 3) ? (seg == 0 ? b0 : (seg == 1 ? b1 : b2)) : b0;
    float bv[4];
#pragma unroll
    for (int n = 0; n < 4; ++n) {
        const int col = n0 + wn + n * 16 + fr;
        bv[n] = bias[(ACT == 3) ? (col - seg * 512) : col];
    }

#pragma unroll
    for (int m = 0; m < 4; ++m)
#pragma unroll
        for (int n = 0; n < 4; ++n)
#pragma unroll
            for (int j = 0; j < 4; ++j) {
                const int row = m0 + wm + m * 16 + (lane >> 4) * 4 + j;
                const int col = n0 + wn + n * 16 + fr;
                float v = acc[m][n][j] + bv[n];
                if (ACCUM) v += C32[(size_t)row * N + col];
                if (ACT == 1) v = elu1f(v);
                else if (ACT == 2) v = geluf(v);
                else if (ACT == 3) { if (seg < 2) v = elu1f(v); }
                if (WF32) C32[(size_t)row * N + col] = v;
                if (WBF16) {
                    if (ACT == 3)
                        Cbf[(size_t)seg * SEGSTRIDE + (size_t)row * 512 + (col - seg * 512)] = f2b(v);
                    else
                        Cbf[(size_t)row * N + col] = f2b(v);
                }
            }
}

// ---------------------------------------------------------------------------
// Weight transpose + bf16
// ---------------------------------------------------------------------------
__global__ __launch_bounds__(256) void transpose_to_bf16(
    const float* __restrict__ W, unsigned short* __restrict__ WT, int K, int N)
{
    __shared__ float tile[32][33];
    const int k0 = blockIdx.x * 32, n0 = blockIdx.y * 32;
    const int tx = threadIdx.x & 31, ty = threadIdx.x >> 5;
#pragma unroll
    for (int i = ty; i < 32; i += 8)
        tile[i][tx] = W[(size_t)(k0 + i) * N + n0 + tx];
    __syncthreads();
#pragma unroll
    for (int i = ty; i < 32; i += 8)
        WT[(size_t)(n0 + i) * K + k0 + tx] = f2b(tile[tx][i]);
}

__global__ __launch_bounds__(256) void cvt_in(
    const float* __restrict__ h, float* __restrict__ x,
    unsigned short* __restrict__ xb, int n)
{
    const int i = (blockIdx.x * 256 + threadIdx.x) * 8;
    if (i >= n) return;
    f32x4 a = *(const f32x4*)(h + i);
    f32x4 b = *(const f32x4*)(h + i + 4);
    *(f32x4*)(x + i) = a;
    *(f32x4*)(x + i + 4) = b;
    short8v p;
    p[0] = f2b(a[0]); p[1] = f2b(a[1]); p[2] = f2b(a[2]); p[3] = f2b(a[3]);
    p[4] = f2b(b[0]); p[5] = f2b(b[1]); p[6] = f2b(b[2]); p[7] = f2b(b[3]);
    *(short8v*)(xb + i) = p;
}

// swizzled 64x64 bf16 tile access: logical (row, sl) -> shorts offset
__device__ __forceinline__ int swzo(int row, int sl) {
    return row * 64 + ((sl ^ (row & 7)) << 3);
}

// ---------------------------------------------------------------------------
// Attention stage 1 (MFMA): per (b,h,chunk) KVt[e][d] = sum_j V[j][e]*K[j][d]
// (bf16 out), z[d] = sum_j K[j][d] (f32).
// ---------------------------------------------------------------------------
__global__ __launch_bounds__(256) void attn_stage1(
    const unsigned short* __restrict__ Kf, const unsigned short* __restrict__ Vf,
    unsigned short* __restrict__ KVp, float* __restrict__ zp)
{
    const int c = blockIdx.x, hh = blockIdx.y, bb = blockIdx.z;
    const int t = threadIdx.x;
    const int lane = t & 63, w = t >> 6;
    const int fr = lane & 15, g = lane >> 4;

    __shared__ unsigned short KTs[64 * 72];   // K^T [d][j], pad 72
    __shared__ unsigned short VTs[64 * 72];   // V^T [e][j], pad 72

    const size_t rowbase = (size_t)(bb * S_LEN + c * CHUNK);
    const int colbase = hh * DH;

    {   // transposed staging: thread loads row r, 16 cols at cs; writes columns
        const int r = lane, cs = w * 16;
        const unsigned short* kp = Kf + (rowbase + r) * DMODEL + colbase + cs;
        const unsigned short* vp = Vf + (rowbase + r) * DMODEL + colbase + cs;
        short8v k0 = *(const short8v*)kp, k1 = *(const short8v*)(kp + 8);
        short8v v0 = *(const short8v*)vp, v1 = *(const short8v*)(vp + 8);
#pragma unroll
        for (int i = 0; i < 8; ++i) {
            KTs[(cs + i) * 72 + r]     = (unsigned short)k0[i];
            KTs[(cs + 8 + i) * 72 + r] = (unsigned short)k1[i];
            VTs[(cs + i) * 72 + r]     = (unsigned short)v0[i];
            VTs[(cs + 8 + i) * 72 + r] = (unsigned short)v1[i];
        }
    }
    __syncthreads();

    // C[e][d]: wave w owns e-slice w*16..+15 (m), d = 4 frags (n), k = j (64)
    f32x4 cacc[4];
#pragma unroll
    for (int nf = 0; nf < 4; ++nf) cacc[nf] = (f32x4){0.f, 0.f, 0.f, 0.f};

    const short8v a0 = *(const short8v*)&VTs[(w * 16 + fr) * 72 + g * 8];
    const short8v a1 = *(const short8v*)&VTs[(w * 16 + fr) * 72 + (4 + g) * 8];
#pragma unroll
    for (int nf = 0; nf < 4; ++nf) {
        short8v bq0 = *(const short8v*)&KTs[(nf * 16 + fr) * 72 + g * 8];
        short8v bq1 = *(const short8v*)&KTs[(nf * 16 + fr) * 72 + (4 + g) * 8];
        cacc[nf] = __builtin_amdgcn_mfma_f32_16x16x32_bf16(a0, bq0, cacc[nf], 0, 0, 0);
        cacc[nf] = __builtin_amdgcn_mfma_f32_16x16x32_bf16(a1, bq1, cacc[nf], 0, 0, 0);
    }

    const size_t base = ((size_t)(bb * NH + hh) * NCHUNK + c) * (DH * DH);
#pragma unroll
    for (int nf = 0; nf < 4; ++nf)
#pragma unroll
        for (int reg = 0; reg < 4; ++reg) {
            const int e = w * 16 + g * 4 + reg;
            const int d = nf * 16 + fr;
            KVp[base + e * 64 + d] = f2b(cacc[nf][reg]);
        }

    if (t < 64) {   // z[d] = row-sum of KTs row d
        float s = 0.f;
#pragma unroll
        for (int sl = 0; sl < 8; ++sl) {
            short8v kv = *(const short8v*)&KTs[t * 72 + sl * 8];
#pragma unroll
            for (int i = 0; i < 8; ++i) s += b2f((unsigned short)kv[i]);
        }
        zp[((size_t)(bb * NH + hh) * NCHUNK + c) * DH + t] = s;
    }
}

// ---------------------------------------------------------------------------
// Attention stage 2: exclusive prefix over 32 chunk states per (b,h)
// bf16 partials -> bf16 exclusive states (f32 running sum); z prefix f32.
// ---------------------------------------------------------------------------
__global__ __launch_bounds__(256) void attn_stage2(
    const unsigned short* __restrict__ KVp, unsigned short* __restrict__ KVb,
    float* __restrict__ zp)
{
    const int bh = blockIdx.x;
    const int e = blockIdx.y * 256 + threadIdx.x;
    const size_t base = (size_t)bh * NCHUNK * (DH * DH) + e;
    float run = 0.f;
#pragma unroll 4
    for (int c = 0; c < NCHUNK; ++c) {
        const float tmp = b2f(KVp[base + (size_t)c * (DH * DH)]);
        KVb[base + (size_t)c * (DH * DH)] = f2b(run);
        run += tmp;
    }
    if (blockIdx.y == 0 && threadIdx.x < DH) {
        float rz = 0.f;
        const size_t zb = (size_t)bh * NCHUNK * DH + threadIdx.x;
#pragma unroll 4
        for (int c = 0; c < NCHUNK; ++c) {
            const float tmp = zp[zb + c * DH];
            zp[zb + c * DH] = rz;
            rz += tmp;
        }
    }
}

// ---------------------------------------------------------------------------
// Attention stage 3 (MFMA): per (b,h,chunk of 64):
//  S^T = K Q^T  -> mask j<=i lane-locally -> P (bf16, LDS), den_intra via shfl
//  O = Q KVt_pre^T + P V ;  out = O / (q.z_pre + den_intra + eps)
// 256 threads = 4 waves; wave w owns output rows w*16..+15.
// ---------------------------------------------------------------------------
__global__ __launch_bounds__(256) void attn_stage3(
    const unsigned short* __restrict__ Qf, const unsigned short* __restrict__ Kf,
    const unsigned short* __restrict__ Vf, const unsigned short* __restrict__ KVb,
    const float* __restrict__ zp, unsigned short* __restrict__ Af)
{
    const int c = blockIdx.x, hh = blockIdx.y, bb = blockIdx.z;
    const int t = threadIdx.x;
    const int lane = t & 63, w = t >> 6;
    const int fr = lane & 15, g = lane >> 4;

    __shared__ unsigned short Qs[4096];       // [64][64] swizzled
    __shared__ unsigned short Ks[4096];       // [64][64] swizzled
    __shared__ unsigned short KVts[4096];     // KVt_pre [e][d] swizzled
    __shared__ unsigned short VTs[64 * 72];   // V^T [e][j] pad 72
    __shared__ unsigned short Ps[64 * 72];    // P [i][j] pad 72
    __shared__ float zsh[DH];
    __shared__ float den_lds[64];

    const size_t rowbase = (size_t)(bb * S_LEN + c * CHUNK);
    const int colbase = hh * DH;
    const size_t kvbase = ((size_t)(bb * NH + hh) * NCHUNK + c) * (DH * DH);

    // --- staging ---
#pragma unroll
    for (int iss = 0; iss < 2; ++iss) {
        const int u = iss * 256 + t, row = u >> 3, sl = u & 7;
        const int ssl = (sl ^ (row & 7)) * 8;
        gload16(Qf + (rowbase + row) * DMODEL + colbase + ssl, &Qs[(size_t)u * 8]);
        gload16(Kf + (rowbase + row) * DMODEL + colbase + ssl, &Ks[(size_t)u * 8]);
        gload16(KVb + kvbase + row * 64 + ssl, &KVts[(size_t)u * 8]);
    }
    {   // V^T reg-staged transpose: thread loads row lane, cols w*16..+15
        const int r = lane, cs = w * 16;
        const unsigned short* vp = Vf + (rowbase + r) * DMODEL + colbase + cs;
        short8v v0 = *(const short8v*)vp, v1 = *(const short8v*)(vp + 8);
#pragma unroll
        for (int i = 0; i < 8; ++i) {
            VTs[(cs + i) * 72 + r]     = (unsigned short)v0[i];
            VTs[(cs + 8 + i) * 72 + r] = (unsigned short)v1[i];
        }
    }
    if (t < DH) zsh[t] = zp[((size_t)(bb * NH + hh) * NCHUNK + c) * DH + t];
    __syncthreads();

    // --- GEMM1: S^T[j][i] = sum_d K[j][d] Q[i][d]; wave w: cols i = w*16..+15 ---
    f32x4 c1[4];
#pragma unroll
    for (int mf = 0; mf < 4; ++mf) c1[mf] = (f32x4){0.f, 0.f, 0.f, 0.f};
    {
        const short8v bq0 = *(const short8v*)&Qs[swzo(w * 16 + fr, g)];
        const short8v bq1 = *(const short8v*)&Qs[swzo(w * 16 + fr, 4 + g)];
#pragma unroll
        for (int mf = 0; mf < 4; ++mf) {
            short8v ak0 = *(const short8v*)&Ks[swzo(mf * 16 + fr, g)];
            short8v ak1 = *(const short8v*)&Ks[swzo(mf * 16 + fr, 4 + g)];
            c1[mf] = __builtin_amdgcn_mfma_f32_16x16x32_bf16(ak0, bq0, c1[mf], 0, 0, 0);
            c1[mf] = __builtin_amdgcn_mfma_f32_16x16x32_bf16(ak1, bq1, c1[mf], 0, 0, 0);
        }
    }

    // --- mask + P write + den ---
    const int i_my = w * 16 + fr;
    float dint = 0.f;
#pragma unroll
    for (int mf = 0; mf < 4; ++mf)
#pragma unroll
        for (int reg = 0; reg < 4; ++reg) {
            const int j = mf * 16 + g * 4 + reg;
            const float v = (j <= i_my) ? c1[mf][reg] : 0.f;
            dint += v;
            Ps[i_my * 72 + j] = f2b(v);
        }
    dint += __shfl_xor(dint, 16);
    dint += __shfl_xor(dint, 32);

    float dpre = 0.f;
#pragma unroll
    for (int sl = 0; sl < 8; ++sl) {
        short8v qv = *(const short8v*)&Qs[swzo(i_my, sl)];
#pragma unroll
        for (int e = 0; e < 8; ++e) dpre += b2f((unsigned short)qv[e]) * zsh[sl * 8 + e];
    }
    if (g == 0) den_lds[i_my] = dpre + dint + ATT_EPS;

    // --- GEMM2 (Q @ KVt^T) + GEMM3 (P @ V), accumulated ---
    f32x4 acc[4];
#pragma unroll
    for (int nf = 0; nf < 4; ++nf) acc[nf] = (f32x4){0.f, 0.f, 0.f, 0.f};
    {
        const short8v aq0 = *(const short8v*)&Qs[swzo(w * 16 + fr, g)];
        const short8v aq1 = *(const short8v*)&Qs[swzo(w * 16 + fr, 4 + g)];
#pragma unroll
        for (int nf = 0; nf < 4; ++nf) {
            short8v bkv0 = *(const short8v*)&KVts[swzo(nf * 16 + fr, g)];
            short8v bkv1 = *(const short8v*)&KVts[swzo(nf * 16 + fr, 4 + g)];
            acc[nf] = __builtin_amdgcn_mfma_f32_16x16x32_bf16(aq0, bkv0, acc[nf], 0, 0, 0);
            acc[nf] = __builtin_amdgcn_mfma_f32_16x16x32_bf16(aq1, bkv1, acc[nf], 0, 0, 0);
        }
        const short8v ap0 = *(const short8v*)&Ps[(w * 16 + fr) * 72 + g * 8];
        const short8v ap1 = *(const short8v*)&Ps[(w * 16 + fr) * 72 + (4 + g) * 8];
#pragma unroll
        for (int nf = 0; nf < 4; ++nf) {
            short8v bv0 = *(const short8v*)&VTs[(nf * 16 + fr) * 72 + g * 8];
            short8v bv1 = *(const short8v*)&VTs[(nf * 16 + fr) * 72 + (4 + g) * 8];
            acc[nf] = __builtin_amdgcn_mfma_f32_16x16x32_bf16(ap0, bv0, acc[nf], 0, 0, 0);
            acc[nf] = __builtin_amdgcn_mfma_f32_16x16x32_bf16(ap1, bv1, acc[nf], 0, 0, 0);
        }
    }

    // --- epilogue: divide by den, store bf16 ---
#pragma unroll
    for (int reg = 0; reg < 4; ++reg) {
        const int i = w * 16 + g * 4 + reg;
        const float inv = 1.f / den_lds[i];
        unsigned short* dst = Af + (rowbase + i) * DMODEL + colbase;
#pragma unroll
        for (int nf = 0; nf < 4; ++nf)
            dst[nf * 16 + fr] = f2b(acc[nf][reg] * inv);
    }
}

// ---------------------------------------------------------------------------
// LayerNorm over 512: 4 rows per block (one wave each), in-place; bf16 copy.
// ---------------------------------------------------------------------------
__global__ __launch_bounds__(256) void ln_kernel(float* __restrict__ X,
                                                 const float* __restrict__ g,
                                                 const float* __restrict__ b,
                                                 unsigned short* __restrict__ Xb)
{
    const size_t row = blockIdx.x * 4 + (threadIdx.x >> 6);
    const int t = threadIdx.x & 63;
    float* xr = X + row * DMODEL;
    f32x4 x0 = *(const f32x4*)&xr[t * 4];
    f32x4 x1 = *(const f32x4*)&xr[256 + t * 4];

    float s  = x0[0] + x0[1] + x0[2] + x0[3] + x1[0] + x1[1] + x1[2] + x1[3];
    float sq = x0[0]*x0[0] + x0[1]*x0[1] + x0[2]*x0[2] + x0[3]*x0[3] +
               x1[0]*x1[0] + x1[1]*x1[1] + x1[2]*x1[2] + x1[3]*x1[3];
#pragma unroll
    for (int m = 1; m < 64; m <<= 1) {
        s  += __shfl_xor(s, m);
        sq += __shfl_xor(sq, m);
    }
    const float mu  = s * (1.f / DMODEL);
    const float var = sq * (1.f / DMODEL) - mu * mu;
    const float rr  = rsqrtf(var + LN_EPS);

    const int c0 = t * 4, c1 = 256 + t * 4;
    f32x4 g0 = *(const f32x4*)&g[c0], g1v = *(const f32x4*)&g[c1];
    f32x4 b0 = *(const f32x4*)&b[c0], b1v = *(const f32x4*)&b[c1];
    f32x4 y0, y1;
#pragma unroll
    for (int i = 0; i < 4; ++i) {
        y0[i] = (x0[i] - mu) * rr * g0[i] + b0[i];
        y1[i] = (x1[i] - mu) * rr * g1v[i] + b1v[i];
    }
    *(f32x4*)&xr[c0] = y0;
    *(f32x4*)&xr[c1] = y1;
    if (Xb) {
        unsigned short* xb = Xb + row * DMODEL;
        ushort4 u0, u1;
        u0.x = f2b(y0[0]); u0.y = f2b(y0[1]); u0.z = f2b(y0[2]); u0.w = f2b(y0[3]);
        u1.x = f2b(y1[0]); u1.y = f2b(y1[1]); u1.z = f2b(y1[2]); u1.w = f2b(y1[3]);
        *(ushort4*)&xb[c0] = u0;
        *(ushort4*)&xb[c1] = u1;
    }
}

// ---------------------------------------------------------------------------
extern "C" void kernel_launch(void* const* d_in, const int* in_sizes, int n_in,
                              void* d_out, int out_size, void* d_ws, size_t ws_size,
                              hipStream_t stream)
{
    const float* h   = (const float*)d_in[0];
    const float* Wq  = (const float*)d_in[1];
    const float* bq  = (const float*)d_in[2];
    const float* Wk  = (const float*)d_in[3];
    const float* bk  = (const float*)d_in[4];
    const float* Wv  = (const float*)d_in[5];
    const float* bv  = (const float*)d_in[6];
    const float* Wo  = (const float*)d_in[7];
    const float* bo  = (const float*)d_in[8];
    const float* W1  = (const float*)d_in[9];
    const float* b1  = (const float*)d_in[10];
    const float* W2  = (const float*)d_in[11];
    const float* b2  = (const float*)d_in[12];
    const float* g1  = (const float*)d_in[13];
    const float* be1 = (const float*)d_in[14];
    const float* g2  = (const float*)d_in[15];
    const float* be2 = (const float*)d_in[16];
    const float* gf  = (const float*)d_in[17];
    const float* bef = (const float*)d_in[18];

    float* x = (float*)d_out;                     // running activation f32 [8192,512]
    char* ws = (char*)d_ws;
    const size_t MB = 1024 * 1024;
    unsigned short* x_bf = (unsigned short*)(ws);                 // 8 MB
    unsigned short* qkv  = (unsigned short*)(ws + 8 * MB);        // q|k|v 24 MB
    unsigned short* qb   = qkv;
    unsigned short* kb   = qkv + SEGSTRIDE;
    unsigned short* vb   = qkv + 2 * (size_t)SEGSTRIDE;
    unsigned short* ab   = (unsigned short*)(ws + 32 * MB);       // 8 MB
    unsigned short* hid  = (unsigned short*)(ws + 8 * MB);        // 32 MB alias q|k|v|a
    unsigned short* KVp  = (unsigned short*)(ws + 40 * MB);       // partials bf16 8 MB
    unsigned short* KVb  = (unsigned short*)(ws + 48 * MB);       // prefix states 8 MB
    float* zp            = (float*)(ws + 56 * MB);                // 0.5 MB
    unsigned short* WTall = (unsigned short*)(ws + 57 * MB);      // 24 MB

    const int M = MROWS, D = DMODEL, DF = DFF;
    const size_t LSTR = 3 * 1024 * 1024;

    cvt_in<<<dim3(M * D / (256 * 8)), 256, 0, stream>>>(h, x, x_bf, M * D);
    for (int l = 0; l < LAYERS; ++l) {
        unsigned short* WL = WTall + (size_t)l * LSTR;
        transpose_to_bf16<<<dim3(D / 32, D / 32), 256, 0, stream>>>(Wq + (size_t)l * D * D, WL, D, D);
        transpose_to_bf16<<<dim3(D / 32, D / 32), 256, 0, stream>>>(Wk + (size_t)l * D * D, WL + 262144, D, D);
        transpose_to_bf16<<<dim3(D / 32, D / 32), 256, 0, stream>>>(Wv + (size_t)l * D * D, WL + 524288, D, D);
        transpose_to_bf16<<<dim3(D / 32, D / 32), 256, 0, stream>>>(Wo + (size_t)l * D * D, WL + 786432, D, D);
        transpose_to_bf16<<<dim3(D / 32, DF / 32), 256, 0, stream>>>(W1 + (size_t)l * D * DF, WL + 1048576, D, DF);
        transpose_to_bf16<<<dim3(DF / 32, D / 32), 256, 0, stream>>>(W2 + (size_t)l * DF * D, WL + 2097152, DF, D);
    }

    for (int l = 0; l < LAYERS; ++l) {
        unsigned short* WL = WTall + (size_t)l * LSTR;
        const unsigned short* WqkvT = WL;            // [1536][512]
        const unsigned short* WoT   = WL + 786432;   // [512][512]
        const unsigned short* W1T   = WL + 1048576;  // [2048][512]
        const unsigned short* W2T   = WL + 2097152;  // [512][2048]

        gemm_bf16<3, false, false, true><<<dim3(M / 128, 1536 / 128), 256, 0, stream>>>(
            x_bf, WqkvT, bq + (size_t)l * D, bk + (size_t)l * D, bv + (size_t)l * D,
            nullptr, qkv, M, 1536, D);

        attn_stage1<<<dim3(NCHUNK, NH, NB), 256, 0, stream>>>(kb, vb, KVp, zp);
        attn_stage2<<<dim3(NB * NH, 16), 256, 0, stream>>>(KVp, KVb, zp);
        attn_stage3<<<dim3(NCHUNK, NH, NB), 256, 0, stream>>>(qb, kb, vb, KVb, zp, ab);

        gemm_bf16<0, true, true, false><<<dim3(M / 128, D / 128), 256, 0, stream>>>(
            ab, WoT, bo + (size_t)l * D, nullptr, nullptr, x, nullptr, M, D, D);
        ln_kernel<<<dim3(M / 4), 256, 0, stream>>>(x, g1 + (size_t)l * D, be1 + (size_t)l * D, x_bf);

        gemm_bf16<2, false, false, true><<<dim3(M / 128, DF / 128), 256, 0, stream>>>(
            x_bf, W1T, b1 + (size_t)l * DF, nullptr, nullptr, nullptr, hid, M, DF, D);
        gemm_bf16<0, true, true, false><<<dim3(M / 128, D / 128), 256, 0, stream>>>(
            hid, W2T, b2 + (size_t)l * D, nullptr, nullptr, x, nullptr, M, D, DF);
        ln_kernel<<<dim3(M / 4), 256, 0, stream>>>(x, g2 + (size_t)l * D, be2 + (size_t)l * D, x_bf);
    }

    ln_kernel<<<dim3(M / 4), 256, 0, stream>>>(x, gf, bef, nullptr);
}